// Round 4
// baseline (429.218 us; speedup 1.0000x reference)
//
#include <hip/hip_runtime.h>
#include <math.h>

#define N_ 4
#define C_ 64
#define H_ 128
#define W_ 128
#define HW_ (H_ * W_)
#define K2_ 9
#define COUT 64
#define CK 576          // C_*K2_
#define TP 16           // pixels per block
#define SST 584         // s_x row stride (elements), 584*2B: 16B-aligned rows
#define CST 258         // s_tile per-channel stride (elems): 129 dwords (odd) -> bank spread
#define TROWS 8
#define TCOLS 32

typedef __bf16 bf16x8 __attribute__((ext_vector_type(8)));
typedef float floatx4 __attribute__((ext_vector_type(4)));
typedef float floatx8 __attribute__((ext_vector_type(8)));

// A-rows (fp32 global, converted in-register) x B (bf16 LDS) -> 16x16 tile
__device__ __forceinline__ floatx4 gemm_tile(const float* __restrict__ arow,
                                             const __bf16* __restrict__ brow) {
    floatx4 acc = {0.f, 0.f, 0.f, 0.f};
#pragma unroll 3
    for (int it = 0; it < 18; ++it) {
        bf16x8 a = __builtin_convertvector(*(const floatx8*)(arow + 32 * it), bf16x8);
        bf16x8 bb = *(const bf16x8*)(brow + 32 * it);
        acc = __builtin_amdgcn_mfma_f32_16x16x32_bf16(a, bb, acc, 0, 0, 0);
    }
    return acc;
}

__global__ __launch_bounds__(256) void fused_kernel(const float* __restrict__ x,
                                                    const float* __restrict__ w_off,
                                                    const float* __restrict__ b_off,
                                                    const float* __restrict__ w,
                                                    const float* __restrict__ b,
                                                    float* __restrict__ out) {
    __shared__ __align__(16) __bf16 s_tile[C_ * CST];      // x window [c][8][32], bf16
    __shared__ __align__(16) __bf16 s_x[TP * SST];         // B^T tile [p][ck]
    __shared__ float s_om[32 * TP];                        // offset-conv out [co][p]
    __shared__ floatx4 s_w4[K2_ * TP];                     // 4 position-weights (mask folded)
    __shared__ unsigned short s_boff[K2_ * TP];            // clamped global base offset
    __shared__ unsigned short s_tloc[K2_ * TP];            // tile-local base, 0xFFFF = fallback

    int t = threadIdx.x;
    int pixbase = blockIdx.x * TP;                         // over N*H*W
    int wo0 = pixbase & (W_ - 1);
    int ho  = (pixbase >> 7) & (H_ - 1);
    int n   = pixbase >> 14;
    const float* xn = x + (size_t)n * C_ * HW_;
    int yb = ho - 3;                                       // tile rows yb..yb+7
    int xb = wo0 - 8;                                      // tile cols xb..xb+31

    int p = t & 15;
    int s = t >> 4;

    // ---- Phase S: stage 64ch x 8 x 32 window -> s_tile (bf16, zero-padded) ----
    {
#pragma unroll 4
        for (int i = 0; i < C_; ++i) {                     // i == channel
            int rx = t & 31;
            int ry = (t >> 5) & 7;
            int y  = yb + ry;
            int xg = xb + rx;
            bool valid = ((unsigned)y < (unsigned)H_) && ((unsigned)xg < (unsigned)W_);
            float v = valid ? xn[(unsigned)i * HW_ + y * W_ + xg] : 0.f;
            s_tile[i * CST + ry * TCOLS + rx] = (__bf16)v;
        }
    }
    __syncthreads();

    // ---- Phase A: im2col from tile -> s_x (no conversion, bf16 copy) ----
    {
#pragma unroll
        for (int cc = 0; cc < 4; ++cc) {
            int c = cc * 16 + s;
            const __bf16* tb = s_tile + c * CST;
            __bf16* xrow = s_x + p * SST + c * 9;
#pragma unroll
            for (int k = 0; k < 9; ++k) {
                int kh = k / 3, kw = k - kh * 3;
                xrow[k] = tb[(kh + 2) * TCOLS + (p + 7 + kw)];
            }
        }
    }
    __syncthreads();

    int lane = t & 63;
    int wv   = t >> 6;
    int q    = lane >> 4;
    int col  = lane & 15;
    const __bf16* brow = s_x + col * SST + q * 8;

    // ---- Phase B: offset conv via MFMA (waves 0,1; rows>=27 unused) ----
    if (wv < 2) {
        int row = min(16 * wv + col, 26);
        floatx4 acc = gemm_tile(w_off + (size_t)row * CK + q * 8, brow);
#pragma unroll
        for (int r = 0; r < 4; ++r)
            s_om[(16 * wv + q * 4 + r) * TP + col] = acc[r];
    }
    __syncthreads();

    // ---- coords: position-weights + tile-local / global base (144 threads) ----
    if (t < K2_ * TP) {
        int k  = t >> 4;
        int pp = t & 15;
        float dy = s_om[(2 * k) * TP + pp]     + b_off[2 * k];
        float dx = s_om[(2 * k + 1) * TP + pp] + b_off[2 * k + 1];
        float mm = s_om[(18 + k) * TP + pp]    + b_off[18 + k];
        float msk = 1.f / (1.f + expf(-mm));
        int kh = k / 3, kw = k - kh * 3;
        float py = (float)(ho - 1 + kh) + dy;
        float px = (float)(wo0 + pp - 1 + kw) + dx;
        float yf = floorf(py), xf = floorf(px);
        float fy = py - yf, fx = px - xf;
        int y0 = (int)yf, x0 = (int)xf;
        float wy0 = ((unsigned)y0 < (unsigned)H_)       ? 1.f - fy : 0.f;
        float wy1 = ((unsigned)(y0 + 1) < (unsigned)H_) ? fy       : 0.f;
        float wx0 = ((unsigned)x0 < (unsigned)W_)       ? 1.f - fx : 0.f;
        float wx1 = ((unsigned)(x0 + 1) < (unsigned)W_) ? fx       : 0.f;
        int y0c = min(max(y0, 0), H_ - 2);
        int x0c = min(max(x0, 0), W_ - 2);
        // shift weights onto clamped positions (OOB-safe addresses, exact zeros)
        float t0 = (y0 == y0c) ? wy0 : ((y0 + 1 == y0c) ? wy1 : 0.f);
        float t1 = (y0 == y0c) ? wy1 : ((y0 == y0c + 1) ? wy0 : 0.f);
        float u0 = (x0 == x0c) ? wx0 : ((x0 + 1 == x0c) ? wx1 : 0.f);
        float u1 = (x0 == x0c) ? wx1 : ((x0 == x0c + 1) ? wx0 : 0.f);
        floatx4 w4 = { t0 * u0 * msk, t0 * u1 * msk, t1 * u0 * msk, t1 * u1 * msk };
        s_w4[t] = w4;
        s_boff[t] = (unsigned short)(y0c * W_ + x0c);
        int ry0 = y0c - yb;
        int rx0 = x0c - xb;
        bool intile = ((unsigned)ry0 < (unsigned)(TROWS - 1)) &&
                      ((unsigned)rx0 < (unsigned)(TCOLS - 1));
        s_tloc[t] = intile ? (unsigned short)(ry0 * TCOLS + rx0) : (unsigned short)0xFFFFu;
    }
    __syncthreads();

    // ---- Phase C: bilinear sample from tile (rare global fallback) -> s_x ----
    for (int k = 0; k < 9; ++k) {
        floatx4 w4 = s_w4[k * 16 + p];
        unsigned tl = s_tloc[k * 16 + p];
        unsigned bo = s_boff[k * 16 + p];
#pragma unroll
        for (int cc = 0; cc < 4; ++cc) {
            int c = cc * 16 + s;
            float v00, v01, v10, v11;
            if (tl != 0xFFFFu) {
                const __bf16* tb = s_tile + c * CST + tl;
                v00 = (float)tb[0];
                v01 = (float)tb[1];
                v10 = (float)tb[TCOLS];
                v11 = (float)tb[TCOLS + 1];
            } else {
                const float* xp = xn + (unsigned)c * HW_ + bo;
                v00 = xp[0];
                v01 = xp[1];
                v10 = xp[W_];
                v11 = xp[W_ + 1];
            }
            float v = w4[0] * v00 + w4[1] * v01 + w4[2] * v10 + w4[3] * v11;
            s_x[p * SST + c * 9 + k] = (__bf16)v;
        }
    }
    __syncthreads();

    // ---- Phase D: main conv MFMA (4 waves) + bias + relu ----
    {
        int row = 16 * wv + col;
        floatx4 acc = gemm_tile(w + (size_t)row * CK + q * 8, brow);
#pragma unroll
        for (int r = 0; r < 4; ++r) {
            int o = 16 * wv + q * 4 + r;
            float v = acc[r] + b[o];
            out[(((size_t)n * COUT + o) * H_ + ho) * W_ + wo0 + col] = fmaxf(v, 0.f);
        }
    }
}

extern "C" void kernel_launch(void* const* d_in, const int* in_sizes, int n_in,
                              void* d_out, int out_size, void* d_ws, size_t ws_size,
                              hipStream_t stream) {
    const float* x     = (const float*)d_in[0];
    const float* w_off = (const float*)d_in[1];
    const float* b_off = (const float*)d_in[2];
    const float* w     = (const float*)d_in[3];
    const float* b     = (const float*)d_in[4];
    float* out = (float*)d_out;

    int nblocks = N_ * H_ * W_ / TP;   // 4096
    fused_kernel<<<nblocks, 256, 0, stream>>>(x, w_off, b_off, w, b, out);
}

// Round 5
// 230.305 us; speedup vs baseline: 1.8637x; 1.8637x over previous
//
#include <hip/hip_runtime.h>
#include <math.h>

#define N_ 4
#define C_ 64
#define H_ 128
#define W_ 128
#define HW_ (H_ * W_)
#define K2_ 9
#define COUT 64
#define CK 576          // C_*K2_
#define TP 16           // pixels per block
#define SST 584         // s_x row stride (elements), 584*2B: 16B-aligned rows

typedef __bf16 bf16x8 __attribute__((ext_vector_type(8)));
typedef float floatx4 __attribute__((ext_vector_type(4)));
typedef float floatx8 __attribute__((ext_vector_type(8)));

// A-rows (fp32 global, converted in-register) x B (bf16 LDS) -> 16x16 tile
__device__ __forceinline__ floatx4 gemm_tile(const float* __restrict__ arow,
                                             const __bf16* __restrict__ brow) {
    floatx4 acc = {0.f, 0.f, 0.f, 0.f};
#pragma unroll 3
    for (int it = 0; it < 18; ++it) {
        bf16x8 a = __builtin_convertvector(*(const floatx8*)(arow + 32 * it), bf16x8);
        bf16x8 bb = *(const bf16x8*)(brow + 32 * it);
        acc = __builtin_amdgcn_mfma_f32_16x16x32_bf16(a, bb, acc, 0, 0, 0);
    }
    return acc;
}

__global__ __launch_bounds__(256) void fused_kernel(const float* __restrict__ x,
                                                    const float* __restrict__ w_off,
                                                    const float* __restrict__ b_off,
                                                    const float* __restrict__ w,
                                                    const float* __restrict__ b,
                                                    float* __restrict__ out) {
    __shared__ __align__(16) __bf16 s_x[TP * SST];         // B^T tile [p][ck]
    __shared__ float s_om[32 * TP];                        // offset-conv out [co][p]
    __shared__ floatx4 s_w4[K2_ * TP];                     // 4 position-weights (mask folded)
    __shared__ unsigned short s_boff[K2_ * TP];            // clamped base element offset

    int t = threadIdx.x;
    int pixbase = blockIdx.x * TP;                         // over N*H*W
    int wo0 = pixbase & (W_ - 1);
    int ho  = (pixbase >> 7) & (H_ - 1);
    int n   = pixbase >> 14;
    const float* xn = x + (size_t)n * C_ * HW_;

    int p = t & 15;            // pixel
    int s = t >> 4;            // 0..15 (channel sub-index)

    // ---- Phase A: integer-tap im2col, loads BATCHED per channel-chunk ----
    {
        unsigned aofs[9];
        float amask[9];
#pragma unroll
        for (int k = 0; k < 9; ++k) {
            int kh = k / 3, kw = k - kh * 3;
            int y  = ho - 1 + kh;
            int xx = wo0 + p - 1 + kw;
            bool valid = ((unsigned)y < (unsigned)H_) && ((unsigned)xx < (unsigned)W_);
            int yc  = min(max(y, 0), H_ - 1);
            int xcl = min(max(xx, 0), W_ - 1);
            aofs[k]  = (unsigned)(yc * W_ + xcl);
            amask[k] = valid ? 1.f : 0.f;
        }
#pragma unroll
        for (int cc = 0; cc < 4; ++cc) {
            int c = cc * 16 + s;
            const float* xc = xn + (unsigned)c * HW_;
            float vals[9];
#pragma unroll
            for (int k = 0; k < 9; ++k) vals[k] = xc[aofs[k]];   // 9 loads in flight
            __bf16* xrow = s_x + p * SST + c * 9;
#pragma unroll
            for (int k = 0; k < 9; ++k) xrow[k] = (__bf16)(vals[k] * amask[k]);
        }
    }
    __syncthreads();

    int lane = t & 63;
    int wv   = t >> 6;
    int q    = lane >> 4;
    int col  = lane & 15;
    const __bf16* brow = s_x + col * SST + q * 8;

    // ---- Phase B: offset conv via MFMA (waves 0,1; rows>=27 unused) ----
    if (wv < 2) {
        int row = min(16 * wv + col, 26);
        floatx4 acc = gemm_tile(w_off + (size_t)row * CK + q * 8, brow);
#pragma unroll
        for (int r = 0; r < 4; ++r)
            s_om[(16 * wv + q * 4 + r) * TP + col] = acc[r];
    }
    __syncthreads();

    // ---- coords: position-weights + clamped base offset (144 threads) ----
    if (t < K2_ * TP) {
        int k  = t >> 4;
        int pp = t & 15;
        float dy = s_om[(2 * k) * TP + pp]     + b_off[2 * k];
        float dx = s_om[(2 * k + 1) * TP + pp] + b_off[2 * k + 1];
        float mm = s_om[(18 + k) * TP + pp]    + b_off[18 + k];
        float msk = 1.f / (1.f + expf(-mm));
        int kh = k / 3, kw = k - kh * 3;
        float py = (float)(ho - 1 + kh) + dy;
        float px = (float)(wo0 + pp - 1 + kw) + dx;
        float yf = floorf(py), xf = floorf(px);
        float fy = py - yf, fx = px - xf;
        int y0 = (int)yf, x0 = (int)xf;
        float wy0 = ((unsigned)y0 < (unsigned)H_)       ? 1.f - fy : 0.f;
        float wy1 = ((unsigned)(y0 + 1) < (unsigned)H_) ? fy       : 0.f;
        float wx0 = ((unsigned)x0 < (unsigned)W_)       ? 1.f - fx : 0.f;
        float wx1 = ((unsigned)(x0 + 1) < (unsigned)W_) ? fx       : 0.f;
        int y0c = min(max(y0, 0), H_ - 2);
        int x0c = min(max(x0, 0), W_ - 2);
        // shift weights onto clamped positions (OOB-safe addresses, exact zeros)
        float t0 = (y0 == y0c) ? wy0 : ((y0 + 1 == y0c) ? wy1 : 0.f);
        float t1 = (y0 == y0c) ? wy1 : ((y0 == y0c + 1) ? wy0 : 0.f);
        float u0 = (x0 == x0c) ? wx0 : ((x0 + 1 == x0c) ? wx1 : 0.f);
        float u1 = (x0 == x0c) ? wx1 : ((x0 == x0c + 1) ? wx0 : 0.f);
        floatx4 w4 = { t0 * u0 * msk, t0 * u1 * msk, t1 * u0 * msk, t1 * u1 * msk };
        s_w4[t] = w4;
        s_boff[t] = (unsigned short)(y0c * W_ + x0c);
    }
    __syncthreads();

    // ---- Phase C: bilinear sample, 36 tap loads BATCHED per channel-chunk ----
    {
        unsigned bok[9];
#pragma unroll
        for (int k = 0; k < 9; ++k) bok[k] = s_boff[k * 16 + p];
#pragma unroll
        for (int cc = 0; cc < 4; ++cc) {
            int c = cc * 16 + s;
            const float* xc = xn + (unsigned)c * HW_;
            float v00[9], v01[9], v10[9], v11[9];
#pragma unroll
            for (int k = 0; k < 9; ++k) {                 // 36 loads in flight
                const float* xp = xc + bok[k];
                v00[k] = xp[0];
                v01[k] = xp[1];
                v10[k] = xp[W_];
                v11[k] = xp[W_ + 1];
            }
            __bf16* xrow = s_x + p * SST + c * 9;
#pragma unroll
            for (int k = 0; k < 9; ++k) {
                floatx4 w4 = s_w4[k * 16 + p];
                float v = w4[0] * v00[k] + w4[1] * v01[k]
                        + w4[2] * v10[k] + w4[3] * v11[k];
                xrow[k] = (__bf16)v;
            }
        }
    }
    __syncthreads();

    // ---- Phase D: main conv MFMA (4 waves) + bias + relu ----
    {
        int row = 16 * wv + col;
        floatx4 acc = gemm_tile(w + (size_t)row * CK + q * 8, brow);
#pragma unroll
        for (int r = 0; r < 4; ++r) {
            int o = 16 * wv + q * 4 + r;
            float v = acc[r] + b[o];
            out[(((size_t)n * COUT + o) * H_ + ho) * W_ + wo0 + col] = fmaxf(v, 0.f);
        }
    }
}

extern "C" void kernel_launch(void* const* d_in, const int* in_sizes, int n_in,
                              void* d_out, int out_size, void* d_ws, size_t ws_size,
                              hipStream_t stream) {
    const float* x     = (const float*)d_in[0];
    const float* w_off = (const float*)d_in[1];
    const float* b_off = (const float*)d_in[2];
    const float* w     = (const float*)d_in[3];
    const float* b     = (const float*)d_in[4];
    float* out = (float*)d_out;

    int nblocks = N_ * H_ * W_ / TP;   // 4096
    fused_kernel<<<nblocks, 256, 0, stream>>>(x, w_off, b_off, w, b, out);
}

// Round 6
// 163.876 us; speedup vs baseline: 2.6192x; 1.4054x over previous
//
#include <hip/hip_runtime.h>
#include <math.h>

#define N_ 4
#define C_ 64
#define H_ 128
#define W_ 128
#define HW_ (H_ * W_)
#define K2_ 9
#define COUT 64
#define CK 576          // C_*K2_
#define TP 16           // pixels per block
#define SST 584         // s_x row stride (elems); row bytes 1168 (16B aligned)

typedef __bf16 bf16x8 __attribute__((ext_vector_type(8)));
typedef float floatx4 __attribute__((ext_vector_type(4)));

__device__ __forceinline__ unsigned short f2b(float f) {
    unsigned int u = __builtin_bit_cast(unsigned int, f);
    u = (u + 0x7fffu + ((u >> 16) & 1u)) >> 16;   // RNE
    return (unsigned short)u;
}
__device__ __forceinline__ float bflo(unsigned u) {
    return __builtin_bit_cast(float, u << 16);
}
__device__ __forceinline__ float bfhi(unsigned u) {
    return __builtin_bit_cast(float, u & 0xffff0000u);
}

// ---- transpose x: NCHW fp32 -> NHWC bf16 (LDS-tiled, coalesced both sides) ----
__global__ __launch_bounds__(256) void transpose_kernel(const float* __restrict__ x,
                                                        __bf16* __restrict__ xT) {
    __shared__ float s_t[64][33];
    int x0 = blockIdx.x * 32;
    int y  = blockIdx.y;
    int n  = blockIdx.z;
    int t  = threadIdx.x;
#pragma unroll
    for (int cc = 0; cc < 8; ++cc) {
        int c  = cc * 8 + (t >> 5);
        int xl = t & 31;
        s_t[c][xl] = x[(((size_t)n * C_ + c) * H_ + y) * W_ + x0 + xl];
    }
    __syncthreads();
    __bf16* ob = xT + ((size_t)(n * H_ + y) * W_ + x0) * C_;
#pragma unroll
    for (int i = 0; i < 8; ++i) {
        int xl = i * 4 + (t >> 6);
        int c  = t & 63;
        ob[xl * C_ + c] = (__bf16)s_t[c][xl];
    }
}

// ---- prep: w[o][c][k] -> w2[o][k*64+c] bf16 ; w_off likewise, padded to 32 rows ----
__global__ __launch_bounds__(256) void prep_kernel(const float* __restrict__ w,
                                                   const float* __restrict__ w_off,
                                                   __bf16* __restrict__ w2,
                                                   __bf16* __restrict__ w_off2) {
    int i = blockIdx.x * 256 + threadIdx.x;
    if (i < COUT * CK) {
        int o = i / CK, r = i - o * CK;
        int k = r >> 6, c = r & 63;
        w2[i] = (__bf16)w[(o * C_ + c) * K2_ + k];
    }
    if (i < 32 * CK) {
        int o = i / CK, r = i - o * CK;
        int k = r >> 6, c = r & 63;
        w_off2[i] = (o < 27) ? (__bf16)w_off[(o * C_ + c) * K2_ + k] : (__bf16)0.f;
    }
}

// bf16 A (global) x bf16 B (LDS) -> 16x16 tile, K order = k*64+c
__device__ __forceinline__ floatx4 gemm_tile(const __bf16* __restrict__ arow,
                                             const __bf16* __restrict__ brow) {
    floatx4 acc = {0.f, 0.f, 0.f, 0.f};
#pragma unroll
    for (int it = 0; it < 18; ++it) {
        bf16x8 a  = *(const bf16x8*)(arow + 32 * it);
        bf16x8 bb = *(const bf16x8*)(brow + 32 * it);
        acc = __builtin_amdgcn_mfma_f32_16x16x32_bf16(a, bb, acc, 0, 0, 0);
    }
    return acc;
}

__global__ __launch_bounds__(256) void fused_kernel(const __bf16* __restrict__ xT,
                                                    const __bf16* __restrict__ w2,
                                                    const __bf16* __restrict__ w_off2,
                                                    const float* __restrict__ b_off,
                                                    const float* __restrict__ b,
                                                    float* __restrict__ out) {
    __shared__ __align__(16) __bf16 s_x[TP * SST];   // B^T tile [p][k*64+c]
    __shared__ float s_om[32 * TP];                  // offset-conv out [co][p]
    __shared__ floatx4 s_w4[K2_ * TP];               // 4 position-weights (mask folded)
    __shared__ int s_pix[K2_ * TP];                  // clamped base pixel index

    int t = threadIdx.x;
    int pixbase = blockIdx.x * TP;                   // over N*H*W
    int wo0 = pixbase & (W_ - 1);
    int ho  = (pixbase >> 7) & (H_ - 1);
    int n   = pixbase >> 14;
    const __bf16* xn = xT + (size_t)n * HW_ * C_;

    int lane = t & 63;
    int wv   = t >> 6;

    // ---- Phase A: integer-tap im2col (coalesced NHWC reads, 18 loads in flight) ----
    {
        int half = lane >> 5;
        int li   = lane & 31;
        unsigned ua[18];
#pragma unroll
        for (int j = 0; j < 18; ++j) {
            int P = wv * 36 + 2 * j + half;          // P = k*16 + p
            int k = P >> 4, p = P & 15;
            int kh = k / 3, kw = k - kh * 3;
            int y  = ho - 1 + kh;
            int xx = wo0 + p - 1 + kw;
            int yc  = min(max(y, 0), H_ - 1);
            int xc2 = min(max(xx, 0), W_ - 1);
            unsigned pix = (unsigned)(yc * W_ + xc2);
            ua[j] = *(const unsigned*)(xn + (size_t)pix * C_ + 2 * li);
        }
#pragma unroll
        for (int j = 0; j < 18; ++j) {
            int P = wv * 36 + 2 * j + half;
            int k = P >> 4, p = P & 15;
            int kh = k / 3, kw = k - kh * 3;
            int y  = ho - 1 + kh;
            int xx = wo0 + p - 1 + kw;
            bool valid = ((unsigned)y < (unsigned)H_) && ((unsigned)xx < (unsigned)W_);
            unsigned v = valid ? ua[j] : 0u;
            *(unsigned*)&s_x[p * SST + k * 64 + 2 * li] = v;
        }
    }
    __syncthreads();

    int q   = lane >> 4;
    int col = lane & 15;
    const __bf16* brow = s_x + col * SST + q * 8;

    // ---- Phase B: offset conv via MFMA (waves 0,1; rows>=27 unused) ----
    if (wv < 2) {
        int row = min(16 * wv + col, 26);
        floatx4 acc = gemm_tile(w_off2 + (size_t)row * CK + q * 8, brow);
#pragma unroll
        for (int r = 0; r < 4; ++r)
            s_om[(16 * wv + q * 4 + r) * TP + col] = acc[r];
    }
    __syncthreads();

    // ---- coords: position-weights + clamped base pixel (144 threads) ----
    if (t < K2_ * TP) {
        int k  = t >> 4;
        int pp = t & 15;
        float dy = s_om[(2 * k) * TP + pp]     + b_off[2 * k];
        float dx = s_om[(2 * k + 1) * TP + pp] + b_off[2 * k + 1];
        float mm = s_om[(18 + k) * TP + pp]    + b_off[18 + k];
        float msk = 1.f / (1.f + expf(-mm));
        int kh = k / 3, kw = k - kh * 3;
        float py = (float)(ho - 1 + kh) + dy;
        float px = (float)(wo0 + pp - 1 + kw) + dx;
        float yf = floorf(py), xf = floorf(px);
        float fy = py - yf, fx = px - xf;
        int y0 = (int)yf, x0 = (int)xf;
        float wy0 = ((unsigned)y0 < (unsigned)H_)       ? 1.f - fy : 0.f;
        float wy1 = ((unsigned)(y0 + 1) < (unsigned)H_) ? fy       : 0.f;
        float wx0 = ((unsigned)x0 < (unsigned)W_)       ? 1.f - fx : 0.f;
        float wx1 = ((unsigned)(x0 + 1) < (unsigned)W_) ? fx       : 0.f;
        int y0c = min(max(y0, 0), H_ - 2);
        int x0c = min(max(x0, 0), W_ - 2);
        // shift weights onto clamped positions (OOB-safe addresses, exact zeros)
        float t0 = (y0 == y0c) ? wy0 : ((y0 + 1 == y0c) ? wy1 : 0.f);
        float t1 = (y0 == y0c) ? wy1 : ((y0 == y0c + 1) ? wy0 : 0.f);
        float u0 = (x0 == x0c) ? wx0 : ((x0 + 1 == x0c) ? wx1 : 0.f);
        float u1 = (x0 == x0c) ? wx1 : ((x0 == x0c + 1) ? wx0 : 0.f);
        floatx4 w4 = { t0 * u0 * msk, t0 * u1 * msk, t1 * u0 * msk, t1 * u1 * msk };
        s_w4[t] = w4;
        s_pix[t] = y0c * W_ + x0c;
    }
    __syncthreads();

    // ---- Phase C: bilinear sample, coalesced NHWC, software-pipelined x6 ----
    {
        const int G = 6;
        unsigned bu1[2][G], bu2[2][G];
        int Pb = wv * 36;
#pragma unroll
        for (int j = 0; j < G; ++j) {                 // prologue: group 0 loads
            int pix = s_pix[Pb + j];
            const unsigned* base = (const unsigned*)(xn + (size_t)pix * C_);
            bu1[0][j] = base[lane];                   // row y0: taps x0,x0+1 (256B)
            bu2[0][j] = base[W_ * 32 + lane];         // row y0+1
        }
#pragma unroll
        for (int g = 0; g < 6; ++g) {
            int cur = g & 1;
            if (g < 5) {
#pragma unroll
                for (int j = 0; j < G; ++j) {         // issue group g+1
                    int pix = s_pix[Pb + (g + 1) * G + j];
                    const unsigned* base = (const unsigned*)(xn + (size_t)pix * C_);
                    bu1[cur ^ 1][j] = base[lane];
                    bu2[cur ^ 1][j] = base[W_ * 32 + lane];
                }
            }
#pragma unroll
            for (int j = 0; j < G; ++j) {             // combine group g
                int P = Pb + g * G + j;
                int k = P >> 4, p = P & 15;
                floatx4 w4 = s_w4[P];
                float wA = (lane < 32) ? w4[0] : w4[1];
                float wB = (lane < 32) ? w4[2] : w4[3];
                unsigned u1 = bu1[cur][j], u2 = bu2[cur][j];
                float lo = wA * bflo(u1) + wB * bflo(u2);
                float hi = wA * bfhi(u1) + wB * bfhi(u2);
                lo += __shfl_xor(lo, 32);
                hi += __shfl_xor(hi, 32);
                if (lane < 32) {
                    unsigned res = ((unsigned)f2b(hi) << 16) | (unsigned)f2b(lo);
                    *(unsigned*)&s_x[p * SST + k * 64 + 2 * lane] = res;
                }
            }
        }
    }
    __syncthreads();

    // ---- Phase D: main conv MFMA (4 waves) + bias + relu ----
    {
        int row = 16 * wv + col;
        floatx4 acc = gemm_tile(w2 + (size_t)row * CK + q * 8, brow);
#pragma unroll
        for (int r = 0; r < 4; ++r) {
            int o = 16 * wv + q * 4 + r;
            float v = acc[r] + b[o];
            out[(((size_t)n * COUT + o) * H_ + ho) * W_ + wo0 + col] = fmaxf(v, 0.f);
        }
    }
}

extern "C" void kernel_launch(void* const* d_in, const int* in_sizes, int n_in,
                              void* d_out, int out_size, void* d_ws, size_t ws_size,
                              hipStream_t stream) {
    const float* x     = (const float*)d_in[0];
    const float* w_off = (const float*)d_in[1];
    const float* b_off = (const float*)d_in[2];
    const float* w     = (const float*)d_in[3];
    const float* b     = (const float*)d_in[4];
    float* out = (float*)d_out;

    // workspace: xT (N*H*W*64 bf16 = 8.39 MB) | w2 (64*576 bf16) | w_off2 (32*576 bf16)
    __bf16* xT     = (__bf16*)d_ws;
    __bf16* w2     = xT + (size_t)N_ * HW_ * C_;
    __bf16* w_off2 = w2 + (size_t)COUT * CK;

    dim3 gt(W_ / 32, H_, N_);
    transpose_kernel<<<gt, 256, 0, stream>>>(x, xT);
    prep_kernel<<<(COUT * CK + 255) / 256, 256, 0, stream>>>(w, w_off, w2, w_off2);

    int nblocks = N_ * H_ * W_ / TP;   // 4096
    fused_kernel<<<nblocks, 256, 0, stream>>>(xT, w2, w_off2, b_off, b, out);
}